// Round 3
// baseline (250.169 us; speedup 1.0000x reference)
//
#include <hip/hip_runtime.h>

// y[i,j] = x[i,j] * w[j] + b[j], all FP32.
// x: (8192, 4096) fp32, w/b: (4096,) fp32, out: (8192, 4096) fp32.
// Timed region = ~160 us of harness fill dispatches (fixed) + this kernel.
//
// R3 theory: R2's grid-stride loop serialized each wave (next iteration's loads
// must s_waitcnt the prior stores that read the same VGPRs -> load/store phases
// alternate, 2.4 TB/s). Fix: SINGLE-SHOT waves. Each thread owns 8 float4s at
// slab stride S = GRID*BLOCK (S % 1024 == 0 -> w/b column invariant, loaded once),
// issues 8 independent loads, then 8 fma+stores, then exits. Wave churn across
// 4096 wgs supplies the memory-level parallelism; no loop-carried register hazard.

#define IN_FEATURES 4096
#define VEC 4
#define WVECS (IN_FEATURES / VEC)   // 1024 float4-columns, power of 2

#define BLOCK 256
#define K 8                          // float4s per thread
#define GRID 4096                    // 4096*256*8 = 8,388,608 = nvec exactly; 512 wg/XCD

typedef float f32x4 __attribute__((ext_vector_type(4)));

__global__ __launch_bounds__(BLOCK) void one_to_one_kernel(
        const f32x4* __restrict__ x,
        const f32x4* __restrict__ w,
        const f32x4* __restrict__ b,
        f32x4* __restrict__ out,
        int nvec) {
    const int tid = blockIdx.x * BLOCK + (int)threadIdx.x;
    const int S   = GRID * BLOCK;              // 1,048,576 float4s (16 MiB slabs); S % WVECS == 0

    // Issue the 8 independent streaming loads first (HBM latency critical path).
    f32x4 xv[K];
#pragma unroll
    for (int u = 0; u < K; ++u)
        xv[u] = x[tid + u * S];

    // Column invariant across this thread's 8 elements -> one w/b load (L1/L2 hit).
    const int col = tid & (WVECS - 1);
    const f32x4 wv = w[col];
    const f32x4 bv = b[col];

#pragma unroll
    for (int u = 0; u < K; ++u) {
        f32x4 ov;
        ov.x = fmaf(xv[u].x, wv.x, bv.x);
        ov.y = fmaf(xv[u].y, wv.y, bv.y);
        ov.z = fmaf(xv[u].z, wv.z, bv.z);
        ov.w = fmaf(xv[u].w, wv.w, bv.w);
        out[tid + u * S] = ov;
    }
}

extern "C" void kernel_launch(void* const* d_in, const int* in_sizes, int n_in,
                              void* d_out, int out_size, void* d_ws, size_t ws_size,
                              hipStream_t stream) {
    const f32x4* x = (const f32x4*)d_in[0];    // setup_inputs dict order: x, weight, bias
    const f32x4* w = (const f32x4*)d_in[1];
    const f32x4* b = (const f32x4*)d_in[2];
    f32x4* out = (f32x4*)d_out;

    int nvec = out_size / VEC;                 // 33,554,432 / 4 = 8,388,608
    (void)nvec;                                // GRID*BLOCK*K == nvec exactly for this shape
    one_to_one_kernel<<<GRID, BLOCK, 0, stream>>>(x, w, b, out, nvec);
}

// Round 4
// 226.193 us; speedup vs baseline: 1.1060x; 1.1060x over previous
//
#include <hip/hip_runtime.h>

// y[i,j] = x[i,j] * w[j] + b[j], all FP32.
// x: (8192, 4096) fp32, w/b: (4096,) fp32, out: (8192, 4096) fp32.
// Timed region = ~160 us harness fills (fixed) + this kernel. Kernel floor
// ~43 us at the m13 copy ceiling (268 MB program stream @ 6.29 TB/s).
//
// R4: block-contiguous tiles + FORCED in-flight load bursts.
//  - Ladder so far: R0 naive 1-f4/thread = 63 us; R2/R3 "unrolled" = 83-92 us.
//    R3's VGPR_Count=28 (< 32 needed for 8 live f32x4) proves the compiler
//    re-paired each load with its store (serial load-wait-store), and the
//    8/16-MiB-stride footprints wrecked DRAM/L3 locality on top.
//  - Fix: BLOCK=1024, K=4. Block tile = 4096 consecutive float4s (64 KiB).
//    idx = blockIdx*4096 + u*1024 + tid -> every instruction is a coalesced
//    16 KiB block-wide access; tile contiguous; dispatch order keeps the
//    chip-wide window compact (like R0, unlike R2/R3).
//  - col = idx & 1023 = tid exactly -> w/b loaded ONCE per thread.
//  - Empty asm keep-alive on all 4 loaded values forces them live across the
//    load phase -> 4 loads genuinely in flight, one waitcnt, then 4 fma+store
//    (verifiable: VGPR_Count must rise to ~40+).

#define IN_FEATURES 4096
#define VEC 4
#define WVECS (IN_FEATURES / VEC)   // 1024 float4-columns

#define BLOCK 1024                  // u-stride == BLOCK == WVECS -> col = tid
#define K 4                         // float4s per thread
#define GRID 2048                   // 2048*1024*4 = 8,388,608 = nvec exactly

typedef float f32x4 __attribute__((ext_vector_type(4)));

__global__ __launch_bounds__(BLOCK) void one_to_one_kernel(
        const f32x4* __restrict__ x,
        const f32x4* __restrict__ w,
        const f32x4* __restrict__ b,
        f32x4* __restrict__ out,
        int nvec) {
    const int tid  = (int)threadIdx.x;            // [0, 1024)
    const int base = blockIdx.x * (BLOCK * K) + tid;

    // w/b column is exactly tid for every element this thread touches.
    const f32x4 wv = w[tid];
    const f32x4 bv = b[tid];

    // Burst-issue 4 independent coalesced loads (16 KiB apart, same 64 KiB tile).
    f32x4 x0 = x[base + 0 * BLOCK];
    f32x4 x1 = x[base + 1 * BLOCK];
    f32x4 x2 = x[base + 2 * BLOCK];
    f32x4 x3 = x[base + 3 * BLOCK];

    // Keep all four values live here: forbids the compiler from re-pairing
    // each load with its store (the R2/R3 serialization, VGPR evidence 20/28).
    asm volatile("" : "+v"(x0), "+v"(x1), "+v"(x2), "+v"(x3));

    f32x4 o0, o1, o2, o3;
    o0.x = fmaf(x0.x, wv.x, bv.x); o0.y = fmaf(x0.y, wv.y, bv.y);
    o0.z = fmaf(x0.z, wv.z, bv.z); o0.w = fmaf(x0.w, wv.w, bv.w);
    o1.x = fmaf(x1.x, wv.x, bv.x); o1.y = fmaf(x1.y, wv.y, bv.y);
    o1.z = fmaf(x1.z, wv.z, bv.z); o1.w = fmaf(x1.w, wv.w, bv.w);
    o2.x = fmaf(x2.x, wv.x, bv.x); o2.y = fmaf(x2.y, wv.y, bv.y);
    o2.z = fmaf(x2.z, wv.z, bv.z); o2.w = fmaf(x2.w, wv.w, bv.w);
    o3.x = fmaf(x3.x, wv.x, bv.x); o3.y = fmaf(x3.y, wv.y, bv.y);
    o3.z = fmaf(x3.z, wv.z, bv.z); o3.w = fmaf(x3.w, wv.w, bv.w);

    out[base + 0 * BLOCK] = o0;
    out[base + 1 * BLOCK] = o1;
    out[base + 2 * BLOCK] = o2;
    out[base + 3 * BLOCK] = o3;
}

extern "C" void kernel_launch(void* const* d_in, const int* in_sizes, int n_in,
                              void* d_out, int out_size, void* d_ws, size_t ws_size,
                              hipStream_t stream) {
    const f32x4* x = (const f32x4*)d_in[0];    // setup_inputs dict order: x, weight, bias
    const f32x4* w = (const f32x4*)d_in[1];
    const f32x4* b = (const f32x4*)d_in[2];
    f32x4* out = (f32x4*)d_out;

    int nvec = out_size / VEC;                 // 8,388,608; GRID*BLOCK*K matches exactly
    (void)nvec;
    one_to_one_kernel<<<GRID, BLOCK, 0, stream>>>(x, w, b, out, nvec);
}

// Round 5
// 225.834 us; speedup vs baseline: 1.1078x; 1.0016x over previous
//
#include <hip/hip_runtime.h>

// y[i,j] = x[i,j] * w[j] + b[j], all FP32.
// x: (8192, 4096) fp32, w/b: (4096,) fp32, out: (8192, 4096) fp32.
// Timed region = ~160 us harness fills (fixed, 2x ~80us) + this kernel.
//
// Ladder (kernel-attributable time): R0 naive 1-f4/thread = ~63 us;
// R1 grid-stride+NT(load+store) = ~70; R2 grid-stride = ~83; R3 slab-8 = ~90;
// R4 contiguous burst-4 = ~66. Structure is exhausted; occupancy/MLP/instr
// count are not the limiter (fills reach 6.7 TB/s at 9.5% occupancy).
//
// R5 theory: kernel FETCH_SIZE = 65.6 MB = half of x -> L3 serves half the
// reads across iterations; the OTHER half is evicted by our own out-stores
// write-allocating 134 MB in L2/L3 (data that is never re-read). Single
// change vs R4: NON-TEMPORAL STORES ONLY (loads stay cached). R1 tested
// NT on both paths and regressed because NT LOADS bypass L3 for x — the
// store-side hint was never isolated.
// Predict: FETCH 65.6 -> <=45 MB, kernel 66 -> ~50-58 us, total -> ~210-218.

#define IN_FEATURES 4096
#define VEC 4
#define WVECS (IN_FEATURES / VEC)   // 1024 float4-columns

#define BLOCK 1024                  // u-stride == BLOCK == WVECS -> col = tid
#define K 4                         // float4s per thread
#define GRID 2048                   // 2048*1024*4 = 8,388,608 = nvec exactly

typedef float f32x4 __attribute__((ext_vector_type(4)));

__global__ __launch_bounds__(BLOCK) void one_to_one_kernel(
        const f32x4* __restrict__ x,
        const f32x4* __restrict__ w,
        const f32x4* __restrict__ b,
        f32x4* __restrict__ out,
        int nvec) {
    const int tid  = (int)threadIdx.x;            // [0, 1024)
    const int base = blockIdx.x * (BLOCK * K) + tid;

    // w/b column is exactly tid for every element this thread touches.
    const f32x4 wv = w[tid];
    const f32x4 bv = b[tid];

    // Burst-issue 4 independent coalesced CACHED loads (same 64 KiB tile).
    f32x4 x0 = x[base + 0 * BLOCK];
    f32x4 x1 = x[base + 1 * BLOCK];
    f32x4 x2 = x[base + 2 * BLOCK];
    f32x4 x3 = x[base + 3 * BLOCK];

    // Keep all four live across the load phase (prevents load/store re-pairing).
    asm volatile("" : "+v"(x0), "+v"(x1), "+v"(x2), "+v"(x3));

    f32x4 o0, o1, o2, o3;
    o0.x = fmaf(x0.x, wv.x, bv.x); o0.y = fmaf(x0.y, wv.y, bv.y);
    o0.z = fmaf(x0.z, wv.z, bv.z); o0.w = fmaf(x0.w, wv.w, bv.w);
    o1.x = fmaf(x1.x, wv.x, bv.x); o1.y = fmaf(x1.y, wv.y, bv.y);
    o1.z = fmaf(x1.z, wv.z, bv.z); o1.w = fmaf(x1.w, wv.w, bv.w);
    o2.x = fmaf(x2.x, wv.x, bv.x); o2.y = fmaf(x2.y, wv.y, bv.y);
    o2.z = fmaf(x2.z, wv.z, bv.z); o2.w = fmaf(x2.w, wv.w, bv.w);
    o3.x = fmaf(x3.x, wv.x, bv.x); o3.y = fmaf(x3.y, wv.y, bv.y);
    o3.z = fmaf(x3.z, wv.z, bv.z); o3.w = fmaf(x3.w, wv.w, bv.w);

    // NON-TEMPORAL stores: out is never re-read; don't allocate it in L2/L3,
    // so x stays resident for the next bench iteration (FETCH_SIZE is the check).
    __builtin_nontemporal_store(o0, &out[base + 0 * BLOCK]);
    __builtin_nontemporal_store(o1, &out[base + 1 * BLOCK]);
    __builtin_nontemporal_store(o2, &out[base + 2 * BLOCK]);
    __builtin_nontemporal_store(o3, &out[base + 3 * BLOCK]);
}

extern "C" void kernel_launch(void* const* d_in, const int* in_sizes, int n_in,
                              void* d_out, int out_size, void* d_ws, size_t ws_size,
                              hipStream_t stream) {
    const f32x4* x = (const f32x4*)d_in[0];    // setup_inputs dict order: x, weight, bias
    const f32x4* w = (const f32x4*)d_in[1];
    const f32x4* b = (const f32x4*)d_in[2];
    f32x4* out = (f32x4*)d_out;

    int nvec = out_size / VEC;                 // 8,388,608; GRID*BLOCK*K matches exactly
    (void)nvec;
    one_to_one_kernel<<<GRID, BLOCK, 0, stream>>>(x, w, b, out, nvec);
}

// Round 7
// 221.051 us; speedup vs baseline: 1.1317x; 1.0216x over previous
//
#include <hip/hip_runtime.h>

// y[i,j] = x[i,j] * w[j] + b[j], all FP32.
// x: (8192, 4096) fp32, w/b: (4096,) fp32, out: (8192, 4096) fp32.
// Timed region = ~159 us harness fills (fixed, 2x ~79.5us) + this kernel.
//
// Kernel-attributable ladder: R0 naive = 65; R1 grid-stride+NT(both) = 70;
// R2 grid-stride = 83; R3 slab-8 = 90; R4 contig burst = 66; R5 +NTstore = 67.
// Corrected attribution: WITHIN the grid-stride family NT was -13 us (70 vs 83).
// NT x structure matrix has one untested cell: contiguous burst + NT LOADS.
//
// R6 theory (RERUN — R6 bench was an infra failure, no data): FETCH=65.6MB =
// half of x -> reads are a fine interleave of L3 hits and HBM misses; the HBM
// read stream is sparse -> row-buffer efficiency dies (counter arithmetic:
// write side ~19.7us at fill rate 6.8 TB/s, read side ~46us = 2.9 TB/s, vs
// 5.8 TB/s read-while-write implied by the m13 copy ceiling that runs with a
// cold/dense read stream). NT loads bypass L3 -> x arrives as ONE dense
// sequential HBM stream. Extra 68MB of HBM reads is net-positive if the dense
// stream runs ~2x the sparse rate.
// Predict: kernel FETCH -> ~131072 KB, kernel 67 -> 48-58 us, total -> 207-217.
// If FETCH jumps but time holds ~66: theory dead, revert R4, declare roofline.

#define IN_FEATURES 4096
#define VEC 4
#define WVECS (IN_FEATURES / VEC)   // 1024 float4-columns

#define BLOCK 1024                  // u-stride == BLOCK == WVECS -> col = tid
#define K 4                         // float4s per thread
#define GRID 2048                   // 2048*1024*4 = 8,388,608 = nvec exactly

typedef float f32x4 __attribute__((ext_vector_type(4)));

__global__ __launch_bounds__(BLOCK) void one_to_one_kernel(
        const f32x4* __restrict__ x,
        const f32x4* __restrict__ w,
        const f32x4* __restrict__ b,
        f32x4* __restrict__ out,
        int nvec) {
    const int tid  = (int)threadIdx.x;            // [0, 1024)
    const int base = blockIdx.x * (BLOCK * K) + tid;

    // w/b column is exactly tid for every element this thread touches.
    // These stay CACHED (16 KiB working set, reused by every block).
    const f32x4 wv = w[tid];
    const f32x4 bv = b[tid];

    // Burst-issue 4 independent coalesced NON-TEMPORAL loads (bypass L3 ->
    // dense sequential HBM read stream; same 64 KiB block tile).
    f32x4 x0 = __builtin_nontemporal_load(&x[base + 0 * BLOCK]);
    f32x4 x1 = __builtin_nontemporal_load(&x[base + 1 * BLOCK]);
    f32x4 x2 = __builtin_nontemporal_load(&x[base + 2 * BLOCK]);
    f32x4 x3 = __builtin_nontemporal_load(&x[base + 3 * BLOCK]);

    // Keep all four live across the load phase (prevents load/store re-pairing).
    asm volatile("" : "+v"(x0), "+v"(x1), "+v"(x2), "+v"(x3));

    f32x4 o0, o1, o2, o3;
    o0.x = fmaf(x0.x, wv.x, bv.x); o0.y = fmaf(x0.y, wv.y, bv.y);
    o0.z = fmaf(x0.z, wv.z, bv.z); o0.w = fmaf(x0.w, wv.w, bv.w);
    o1.x = fmaf(x1.x, wv.x, bv.x); o1.y = fmaf(x1.y, wv.y, bv.y);
    o1.z = fmaf(x1.z, wv.z, bv.z); o1.w = fmaf(x1.w, wv.w, bv.w);
    o2.x = fmaf(x2.x, wv.x, bv.x); o2.y = fmaf(x2.y, wv.y, bv.y);
    o2.z = fmaf(x2.z, wv.z, bv.z); o2.w = fmaf(x2.w, wv.w, bv.w);
    o3.x = fmaf(x3.x, wv.x, bv.x); o3.y = fmaf(x3.y, wv.y, bv.y);
    o3.z = fmaf(x3.z, wv.z, bv.z); o3.w = fmaf(x3.w, wv.w, bv.w);

    // NT stores: out is never re-read; don't allocate in L2/L3 (R5: free).
    __builtin_nontemporal_store(o0, &out[base + 0 * BLOCK]);
    __builtin_nontemporal_store(o1, &out[base + 1 * BLOCK]);
    __builtin_nontemporal_store(o2, &out[base + 2 * BLOCK]);
    __builtin_nontemporal_store(o3, &out[base + 3 * BLOCK]);
}

extern "C" void kernel_launch(void* const* d_in, const int* in_sizes, int n_in,
                              void* d_out, int out_size, void* d_ws, size_t ws_size,
                              hipStream_t stream) {
    const f32x4* x = (const f32x4*)d_in[0];    // setup_inputs dict order: x, weight, bias
    const f32x4* w = (const f32x4*)d_in[1];
    const f32x4* b = (const f32x4*)d_in[2];
    f32x4* out = (f32x4*)d_out;

    int nvec = out_size / VEC;                 // 8,388,608; GRID*BLOCK*K matches exactly
    (void)nvec;
    one_to_one_kernel<<<GRID, BLOCK, 0, stream>>>(x, w, b, out, nvec);
}